// Round 1
// baseline (465.713 us; speedup 1.0000x reference)
//
#include <hip/hip_runtime.h>
#include <hip/hip_bf16.h>

#define SEQ   8192
#define NB    8
#define EMB   256
#define NHD   8
#define HDM   32
#define KVSPLIT 16

typedef __attribute__((ext_vector_type(8))) short short8;
typedef __attribute__((ext_vector_type(4))) float floatx4;
typedef __attribute__((ext_vector_type(16))) float floatx16;

__device__ __forceinline__ short f2b(float f) {
    __hip_bfloat16 h = __float2bfloat16(f);
    return __builtin_bit_cast(short, h);
}
__device__ __forceinline__ float b2f(short s) {
    unsigned u = (unsigned)(unsigned short)s << 16;
    return __builtin_bit_cast(float, u);
}

// ---------------------------------------------------------------------------
// Projection GEMM: out[M=65536, N=256] = f( X[M,256] @ W[N,256]^T + bias )
// MODE 0: elu+1 (Q)   MODE 1: elu+1 + Ksum column sums (K)   MODE 2: * 1/SEQ (V)
// 128x128 tile / block, 256 threads (4 waves, each 64x64 via 4x4 of 16x16x32)
// ---------------------------------------------------------------------------
template <int MODE>
__launch_bounds__(256)
__global__ void proj_kernel(const float* __restrict__ X,
                            const float* __restrict__ W,
                            const float* __restrict__ bias,
                            short* __restrict__ out,
                            float* __restrict__ Ksum) {
    __shared__ __align__(16) short As[128 * 64];
    __shared__ __align__(16) short Bs[128 * 64];
    __shared__ float colsum[128];

    const int tid  = threadIdx.x;
    const int tm   = blockIdx.x;
    const int tn   = blockIdx.y;
    const int lane = tid & 63;
    const int wave = tid >> 6;
    const int wm   = (wave & 1) << 6;
    const int wn   = (wave >> 1) << 6;
    const int fr   = lane & 15;
    const int fq   = lane >> 4;

    if (MODE == 1 && tid < 128) colsum[tid] = 0.f;

    floatx4 acc[4][4];
    #pragma unroll
    for (int i = 0; i < 4; i++)
        #pragma unroll
        for (int j = 0; j < 4; j++)
            #pragma unroll
            for (int r = 0; r < 4; r++) acc[i][j][r] = 0.f;

    const int r  = tid >> 1;
    const int c0 = (tid & 1) << 5;
    const float* ap = X + (size_t)(tm * 128 + r) * EMB + c0;
    const float* bp = W + (size_t)(tn * 128 + r) * EMB + c0;

    for (int kc = 0; kc < 4; kc++) {
        const int kb = kc * 64;
        #pragma unroll
        for (int u = 0; u < 8; u++) {
            float4 f = *(const float4*)(ap + kb + 4 * u);
            short4 ha = make_short4(f2b(f.x), f2b(f.y), f2b(f.z), f2b(f.w));
            *(short4*)&As[r * 64 + c0 + 4 * u] = ha;
            float4 g = *(const float4*)(bp + kb + 4 * u);
            short4 hb = make_short4(f2b(g.x), f2b(g.y), f2b(g.z), f2b(g.w));
            *(short4*)&Bs[r * 64 + c0 + 4 * u] = hb;
        }
        __syncthreads();
        #pragma unroll
        for (int kk = 0; kk < 64; kk += 32) {
            short8 a[4], b[4];
            #pragma unroll
            for (int i = 0; i < 4; i++)
                a[i] = *(const short8*)&As[(wm + i * 16 + fr) * 64 + kk + fq * 8];
            #pragma unroll
            for (int j = 0; j < 4; j++)
                b[j] = *(const short8*)&Bs[(wn + j * 16 + fr) * 64 + kk + fq * 8];
            #pragma unroll
            for (int i = 0; i < 4; i++)
                #pragma unroll
                for (int j = 0; j < 4; j++)
                    acc[i][j] = __builtin_amdgcn_mfma_f32_16x16x32_bf16(a[i], b[j], acc[i][j], 0, 0, 0);
        }
        __syncthreads();
    }

    // epilogue
    const int row0 = tm * 128;
    float ks[4] = {0.f, 0.f, 0.f, 0.f};
    #pragma unroll
    for (int i = 0; i < 4; i++) {
        #pragma unroll
        for (int j = 0; j < 4; j++) {
            const int colg = tn * 128 + wn + j * 16 + fr;
            const float bia = bias[colg];
            #pragma unroll
            for (int rr = 0; rr < 4; rr++) {
                const int rowg = row0 + wm + i * 16 + fq * 4 + rr;
                float v = acc[i][j][rr] + bia;
                if (MODE <= 1) v = (v > 0.f) ? (v + 1.f) : __expf(v);   // elu(x)+1
                else           v *= (1.0f / (float)SEQ);
                out[(size_t)rowg * EMB + colg] = f2b(v);
                if (MODE == 1) ks[j] += v;
            }
        }
    }
    if (MODE == 1) {
        #pragma unroll
        for (int j = 0; j < 4; j++)
            atomicAdd(&colsum[wn + j * 16 + fr], ks[j]);
        __syncthreads();
        if (tid < 128) {
            const int b = (tm * 128) / SEQ;
            atomicAdd(&Ksum[b * EMB + tn * 128 + tid], colsum[tid]);
        }
    }
}

// ---------------------------------------------------------------------------
// KV[b,h,d,v] = sum_s Kf[b,s,h,d] * Vn[b,s,h,v]   (split over s, atomicAdd)
// one wave per (b,h,split); lane owns a 4x4 (d,v) tile
// ---------------------------------------------------------------------------
__launch_bounds__(64)
__global__ void kv_kernel(const short* __restrict__ Kf,
                          const short* __restrict__ Vn,
                          float* __restrict__ KV) {
    const int blk  = blockIdx.x;
    const int sp   = blk & (KVSPLIT - 1);
    const int h    = (blk / KVSPLIT) & 7;
    const int b    = blk / (KVSPLIT * 8);
    const int lane = threadIdx.x;
    const int d0   = (lane >> 3) * 4;
    const int v0   = (lane & 7) * 4;
    const int chunk = SEQ / KVSPLIT;

    const short* kp = Kf + (size_t)(b * SEQ + sp * chunk) * EMB + h * 32 + d0;
    const short* vp = Vn + (size_t)(b * SEQ + sp * chunk) * EMB + h * 32 + v0;

    float acc[4][4];
    #pragma unroll
    for (int i = 0; i < 4; i++)
        #pragma unroll
        for (int j = 0; j < 4; j++) acc[i][j] = 0.f;

    for (int s = 0; s < chunk; s++) {
        short4 k4 = *(const short4*)kp; kp += EMB;
        short4 v4 = *(const short4*)vp; vp += EMB;
        float kf[4] = {b2f(k4.x), b2f(k4.y), b2f(k4.z), b2f(k4.w)};
        float vf[4] = {b2f(v4.x), b2f(v4.y), b2f(v4.z), b2f(v4.w)};
        #pragma unroll
        for (int i = 0; i < 4; i++)
            #pragma unroll
            for (int j = 0; j < 4; j++) acc[i][j] += kf[i] * vf[j];
    }

    float* kvp = KV + (size_t)((b * 8 + h) * 32) * 32;
    #pragma unroll
    for (int i = 0; i < 4; i++)
        #pragma unroll
        for (int j = 0; j < 4; j++)
            atomicAdd(&kvp[(d0 + i) * 32 + (v0 + j)], acc[i][j]);
}

// ---------------------------------------------------------------------------
// Mt[b][e][h*32+d] = sum_v KV[b,h,d,v] * Wm[e, h*32+v]   (bf16 out)
// one wave per (b,h,e-tile of 32): C[d(32), e(32)] via 32x32x16 MFMA, K=32
// ---------------------------------------------------------------------------
__launch_bounds__(64)
__global__ void m_kernel(const float* __restrict__ KV,
                         const float* __restrict__ Wm,
                         short* __restrict__ Mt) {
    const int blk  = blockIdx.x;            // 512 = 8b * 8h * 8 e-tiles
    const int e0   = (blk & 7) * 32;
    const int h    = (blk >> 3) & 7;
    const int b    = blk >> 6;
    const int lane = threadIdx.x;
    const int l31  = lane & 31;
    const int q    = lane >> 5;

    floatx16 acc;
    #pragma unroll
    for (int i = 0; i < 16; i++) acc[i] = 0.f;

    #pragma unroll
    for (int kb = 0; kb < 32; kb += 16) {
        const float* ar = KV + (size_t)(((b * 8 + h) * 32 + l31) * 32) + kb + q * 8;
        const float* br = Wm + (size_t)(e0 + l31) * EMB + h * 32 + kb + q * 8;
        short8 a, w;
        #pragma unroll
        for (int t = 0; t < 8; t++) { a[t] = f2b(ar[t]); w[t] = f2b(br[t]); }
        acc = __builtin_amdgcn_mfma_f32_32x32x16_bf16(a, w, acc, 0, 0, 0);
    }

    short* mrow = Mt + (size_t)b * EMB * EMB + (size_t)(e0 + l31) * EMB + h * 32;
    #pragma unroll
    for (int r4 = 0; r4 < 4; r4++) {
        const int dbase = 8 * r4 + 4 * q;   // row = (reg&3) + 8*(reg>>2) + 4*(lane>>5)
        short4 s4 = make_short4(f2b(acc[r4 * 4 + 0]), f2b(acc[r4 * 4 + 1]),
                                f2b(acc[r4 * 4 + 2]), f2b(acc[r4 * 4 + 3]));
        *(short4*)(mrow + dbase) = s4;
    }
}

// ---------------------------------------------------------------------------
// out[t,e] = sum_hd (Qf[t,hd] * zs[t,h]) * Mt[b][e][hd]
// zs[t,h] = SEQ / (Qf[t,h,:]·Ksum[b,h,:] + 1e-6)
// ---------------------------------------------------------------------------
__launch_bounds__(256)
__global__ void out_kernel(const short* __restrict__ Qf,
                           const float* __restrict__ Ksum,
                           const short* __restrict__ Mt,
                           float* __restrict__ Out) {
    __shared__ __align__(16) short As[128 * 64];
    __shared__ __align__(16) short Bs[128 * 64];
    __shared__ float zs[128][NHD];
    __shared__ float ksl[EMB];

    const int tid  = threadIdx.x;
    const int tm   = blockIdx.x;
    const int tn   = blockIdx.y;
    const int b    = (tm * 128) / SEQ;
    const int lane = tid & 63;
    const int wave = tid >> 6;
    const int wm   = (wave & 1) << 6;
    const int wn   = (wave >> 1) << 6;
    const int fr   = lane & 15;
    const int fq   = lane >> 4;

    ksl[tid] = Ksum[b * EMB + tid];
    __syncthreads();

    // zs: thread handles token t = tid>>1, 4 heads
    {
        const int t  = tid >> 1;
        const int h0 = (tid & 1) * 4;
        const short* qrow = Qf + (size_t)(tm * 128 + t) * EMB;
        #pragma unroll
        for (int hh = 0; hh < 4; hh++) {
            const int h = h0 + hh;
            float d = 0.f;
            #pragma unroll
            for (int u = 0; u < 8; u++) {
                short4 q4 = *(const short4*)(qrow + h * 32 + 4 * u);
                d += b2f(q4.x) * ksl[h * 32 + 4 * u + 0] + b2f(q4.y) * ksl[h * 32 + 4 * u + 1]
                   + b2f(q4.z) * ksl[h * 32 + 4 * u + 2] + b2f(q4.w) * ksl[h * 32 + 4 * u + 3];
            }
            zs[t][h] = (float)SEQ / (d + 1e-6f);
        }
    }
    __syncthreads();

    floatx4 acc[4][4];
    #pragma unroll
    for (int i = 0; i < 4; i++)
        #pragma unroll
        for (int j = 0; j < 4; j++)
            #pragma unroll
            for (int r = 0; r < 4; r++) acc[i][j][r] = 0.f;

    const int r  = tid >> 1;
    const int c0 = (tid & 1) << 5;
    const short* ap = Qf + (size_t)(tm * 128 + r) * EMB + c0;
    const short* bp = Mt + (size_t)b * EMB * EMB + (size_t)(tn * 128 + r) * EMB + c0;

    for (int kc = 0; kc < 4; kc++) {
        const int kb = kc * 64;
        const int h  = (kb + c0) >> 5;
        const float z = zs[r][h];
        #pragma unroll
        for (int u = 0; u < 8; u++) {
            short4 q4 = *(const short4*)(ap + kb + 4 * u);
            short4 oa = make_short4(f2b(b2f(q4.x) * z), f2b(b2f(q4.y) * z),
                                    f2b(b2f(q4.z) * z), f2b(b2f(q4.w) * z));
            *(short4*)&As[r * 64 + c0 + 4 * u] = oa;
            *(short4*)&Bs[r * 64 + c0 + 4 * u] = *(const short4*)(bp + kb + 4 * u);
        }
        __syncthreads();
        #pragma unroll
        for (int kk = 0; kk < 64; kk += 32) {
            short8 a[4], bb[4];
            #pragma unroll
            for (int i = 0; i < 4; i++)
                a[i] = *(const short8*)&As[(wm + i * 16 + fr) * 64 + kk + fq * 8];
            #pragma unroll
            for (int j = 0; j < 4; j++)
                bb[j] = *(const short8*)&Bs[(wn + j * 16 + fr) * 64 + kk + fq * 8];
            #pragma unroll
            for (int i = 0; i < 4; i++)
                #pragma unroll
                for (int j = 0; j < 4; j++)
                    acc[i][j] = __builtin_amdgcn_mfma_f32_16x16x32_bf16(a[i], bb[j], acc[i][j], 0, 0, 0);
        }
        __syncthreads();
    }

    const int row0 = tm * 128;
    #pragma unroll
    for (int i = 0; i < 4; i++) {
        #pragma unroll
        for (int j = 0; j < 4; j++) {
            const int colg = tn * 128 + wn + j * 16 + fr;
            #pragma unroll
            for (int rr = 0; rr < 4; rr++) {
                const int rowg = row0 + wm + i * 16 + fq * 4 + rr;
                Out[(size_t)rowg * EMB + colg] = acc[i][j][rr];
            }
        }
    }
}

extern "C" void kernel_launch(void* const* d_in, const int* in_sizes, int n_in,
                              void* d_out, int out_size, void* d_ws, size_t ws_size,
                              hipStream_t stream) {
    (void)in_sizes; (void)n_in; (void)out_size; (void)ws_size;
    const float* q  = (const float*)d_in[0];
    const float* k  = (const float*)d_in[1];
    const float* v  = (const float*)d_in[2];
    const float* Wq = (const float*)d_in[3];
    const float* bq = (const float*)d_in[4];
    const float* Wk = (const float*)d_in[5];
    const float* bk = (const float*)d_in[6];
    const float* Wv = (const float*)d_in[7];
    const float* bv = (const float*)d_in[8];
    const float* Wm = (const float*)d_in[9];

    char* ws = (char*)d_ws;
    short* Qf   = (short*)(ws);                                   // 32 MB bf16
    short* Kf   = (short*)(ws + 33554432);                        // 32 MB bf16
    short* Vn   = (short*)(ws + 67108864);                        // 32 MB bf16
    float* Ksum = (float*)(ws + 100663296);                       // 8 KB
    float* KV   = (float*)(ws + 100663296 + 8192);                // 256 KB
    short* Mt   = (short*)(ws + 100663296 + 8192 + 262144);       // 1 MB bf16

    hipMemsetAsync(ws + 100663296, 0, 8192 + 262144, stream);

    dim3 grid(512, 2), blk(256);
    proj_kernel<0><<<grid, blk, 0, stream>>>(q, Wq, bq, Qf, nullptr);
    proj_kernel<1><<<grid, blk, 0, stream>>>(k, Wk, bk, Kf, Ksum);
    proj_kernel<2><<<grid, blk, 0, stream>>>(v, Wv, bv, Vn, nullptr);
    kv_kernel<<<NB * NHD * KVSPLIT, 64, 0, stream>>>(Kf, Vn, KV);
    m_kernel<<<512, 64, 0, stream>>>(KV, Wm, Mt);
    out_kernel<<<grid, blk, 0, stream>>>(Qf, Ksum, Mt, (float*)d_out);
}

// Round 2
// 429.319 us; speedup vs baseline: 1.0848x; 1.0848x over previous
//
#include <hip/hip_runtime.h>
#include <hip/hip_bf16.h>

#define SEQ   8192
#define NB    8
#define EMB   256
#define NHD   8
#define HDM   32

typedef __attribute__((ext_vector_type(8))) short short8;
typedef __attribute__((ext_vector_type(4))) float floatx4;
typedef __attribute__((ext_vector_type(16))) float floatx16;

__device__ __forceinline__ short f2b(float f) {
    __hip_bfloat16 h = __float2bfloat16(f);
    return __builtin_bit_cast(short, h);
}
__device__ __forceinline__ float b2f(short s) {
    unsigned u = (unsigned)(unsigned short)s << 16;
    return __builtin_bit_cast(float, u);
}

// ---------------------------------------------------------------------------
// Projection GEMM: out[M=65536, N=256] = f( X[M,256] @ W[N,256]^T + bias )
// MODE 0: elu+1 (Q)   MODE 1: elu+1 + Ksum column sums (K)   MODE 2: * 1/SEQ (V)
// ---------------------------------------------------------------------------
template <int MODE>
__launch_bounds__(256)
__global__ void proj_kernel(const float* __restrict__ X,
                            const float* __restrict__ W,
                            const float* __restrict__ bias,
                            short* __restrict__ out,
                            float* __restrict__ Ksum) {
    __shared__ __align__(16) short As[128 * 64];
    __shared__ __align__(16) short Bs[128 * 64];
    __shared__ float colsum[128];

    const int tid  = threadIdx.x;
    const int tm   = blockIdx.x;
    const int tn   = blockIdx.y;
    const int lane = tid & 63;
    const int wave = tid >> 6;
    const int wm   = (wave & 1) << 6;
    const int wn   = (wave >> 1) << 6;
    const int fr   = lane & 15;
    const int fq   = lane >> 4;

    if (MODE == 1 && tid < 128) colsum[tid] = 0.f;

    floatx4 acc[4][4];
    #pragma unroll
    for (int i = 0; i < 4; i++)
        #pragma unroll
        for (int j = 0; j < 4; j++)
            #pragma unroll
            for (int r = 0; r < 4; r++) acc[i][j][r] = 0.f;

    const int r  = tid >> 1;
    const int c0 = (tid & 1) << 5;
    const float* ap = X + (size_t)(tm * 128 + r) * EMB + c0;
    const float* bp = W + (size_t)(tn * 128 + r) * EMB + c0;

    for (int kc = 0; kc < 4; kc++) {
        const int kb = kc * 64;
        #pragma unroll
        for (int u = 0; u < 8; u++) {
            float4 f = *(const float4*)(ap + kb + 4 * u);
            short4 ha = make_short4(f2b(f.x), f2b(f.y), f2b(f.z), f2b(f.w));
            *(short4*)&As[r * 64 + c0 + 4 * u] = ha;
            float4 g = *(const float4*)(bp + kb + 4 * u);
            short4 hb = make_short4(f2b(g.x), f2b(g.y), f2b(g.z), f2b(g.w));
            *(short4*)&Bs[r * 64 + c0 + 4 * u] = hb;
        }
        __syncthreads();
        #pragma unroll
        for (int kk = 0; kk < 64; kk += 32) {
            short8 a[4], b[4];
            #pragma unroll
            for (int i = 0; i < 4; i++)
                a[i] = *(const short8*)&As[(wm + i * 16 + fr) * 64 + kk + fq * 8];
            #pragma unroll
            for (int j = 0; j < 4; j++)
                b[j] = *(const short8*)&Bs[(wn + j * 16 + fr) * 64 + kk + fq * 8];
            #pragma unroll
            for (int i = 0; i < 4; i++)
                #pragma unroll
                for (int j = 0; j < 4; j++)
                    acc[i][j] = __builtin_amdgcn_mfma_f32_16x16x32_bf16(a[i], b[j], acc[i][j], 0, 0, 0);
        }
        __syncthreads();
    }

    const int row0 = tm * 128;
    float ks[4] = {0.f, 0.f, 0.f, 0.f};
    #pragma unroll
    for (int i = 0; i < 4; i++) {
        #pragma unroll
        for (int j = 0; j < 4; j++) {
            const int colg = tn * 128 + wn + j * 16 + fr;
            const float bia = bias[colg];
            #pragma unroll
            for (int rr = 0; rr < 4; rr++) {
                const int rowg = row0 + wm + i * 16 + fq * 4 + rr;
                float v = acc[i][j][rr] + bia;
                if (MODE <= 1) v = (v > 0.f) ? (v + 1.f) : __expf(v);   // elu(x)+1
                else           v *= (1.0f / (float)SEQ);
                out[(size_t)rowg * EMB + colg] = f2b(v);
                if (MODE == 1) ks[j] += v;
            }
        }
    }
    if (MODE == 1) {
        #pragma unroll
        for (int j = 0; j < 4; j++)
            atomicAdd(&colsum[wn + j * 16 + fr], ks[j]);
        __syncthreads();
        if (tid < 128) {
            const int b = (tm * 128) / SEQ;
            atomicAdd(&Ksum[b * EMB + tn * 128 + tid], colsum[tid]);
        }
    }
}

// ---------------------------------------------------------------------------
// KV partials: block (b,sp) stages 32-row tiles of Kf,Vn (full 256 cols,
// coalesced), 4 waves x 2 heads each, per-lane 4x8 register outer product.
// ATOMIC=false: writes KVp[sp][b][h][32][32]; ATOMIC=true: atomicAdd into KV.
// ---------------------------------------------------------------------------
template <bool ATOMIC>
__launch_bounds__(256)
__global__ void kv_kernel(const short* __restrict__ Kf,
                          const short* __restrict__ Vn,
                          float* __restrict__ dst_base,
                          int kvsp) {
    __shared__ __align__(16) short Kt[32 * 256];
    __shared__ __align__(16) short Vt[32 * 256];

    const int tid  = threadIdx.x;
    const int sp   = blockIdx.x % kvsp;
    const int b    = blockIdx.x / kvsp;
    const int wave = tid >> 6;
    const int lane = tid & 63;
    const int h    = wave * 2 + (lane >> 5);
    const int l5   = lane & 31;
    const int d0   = (l5 >> 2) * 4;   // 8 groups of 4 -> 32 d
    const int v0   = (l5 & 3) * 8;    // 4 groups of 8 -> 32 v
    const int chunk = SEQ / kvsp;
    const size_t rowbase = (size_t)(b * SEQ + sp * chunk) * EMB;

    float acc[4][8];
    #pragma unroll
    for (int i = 0; i < 4; i++)
        #pragma unroll
        for (int j = 0; j < 8; j++) acc[i][j] = 0.f;

    for (int t0 = 0; t0 < chunk; t0 += 32) {
        __syncthreads();
        const short* ksrc = Kf + rowbase + (size_t)t0 * EMB;
        const short* vsrc = Vn + rowbase + (size_t)t0 * EMB;
        #pragma unroll
        for (int u = 0; u < 4; u++) {
            const int c   = tid + u * 256;        // 1024 chunks of 8 shorts
            const int row = c >> 5;
            const int col = (c & 31) * 8;
            *(short8*)&Kt[row * 256 + col] = *(const short8*)(ksrc + (size_t)row * EMB + col);
            *(short8*)&Vt[row * 256 + col] = *(const short8*)(vsrc + (size_t)row * EMB + col);
        }
        __syncthreads();
        #pragma unroll 4
        for (int s = 0; s < 32; s++) {
            short4 k4 = *(const short4*)&Kt[s * 256 + h * 32 + d0];
            short8 v8 = *(const short8*)&Vt[s * 256 + h * 32 + v0];
            float kf[4] = {b2f(k4.x), b2f(k4.y), b2f(k4.z), b2f(k4.w)};
            float vf[8];
            #pragma unroll
            for (int j = 0; j < 8; j++) vf[j] = b2f(v8[j]);
            #pragma unroll
            for (int i = 0; i < 4; i++)
                #pragma unroll
                for (int j = 0; j < 8; j++) acc[i][j] += kf[i] * vf[j];
        }
    }

    if (ATOMIC) {
        float* dst = dst_base + (size_t)((b * 8 + h) * 1024);
        #pragma unroll
        for (int i = 0; i < 4; i++)
            #pragma unroll
            for (int j = 0; j < 8; j++)
                atomicAdd(&dst[(d0 + i) * 32 + v0 + j], acc[i][j]);
    } else {
        float* dst = dst_base + (size_t)(((size_t)sp * NB + b) * 8 + h) * 1024;
        #pragma unroll
        for (int i = 0; i < 4; i++) {
            float4 lo = make_float4(acc[i][0], acc[i][1], acc[i][2], acc[i][3]);
            float4 hi = make_float4(acc[i][4], acc[i][5], acc[i][6], acc[i][7]);
            *(float4*)&dst[(d0 + i) * 32 + v0]     = lo;
            *(float4*)&dst[(d0 + i) * 32 + v0 + 4] = hi;
        }
    }
}

// KV[i] = sum_sp KVp[sp][i],  i < 65536
__launch_bounds__(256)
__global__ void kvred_kernel(const float* __restrict__ KVp,
                             float* __restrict__ KV, int kvsp) {
    const int i = blockIdx.x * 1024 + threadIdx.x * 4;
    float4 s = make_float4(0.f, 0.f, 0.f, 0.f);
    for (int p = 0; p < kvsp; p++) {
        float4 t = *(const float4*)&KVp[(size_t)p * 65536 + i];
        s.x += t.x; s.y += t.y; s.z += t.z; s.w += t.w;
    }
    *(float4*)&KV[i] = s;
}

// ---------------------------------------------------------------------------
// Mt[b][e][h*32+d] = sum_v KV[b,h,d,v] * Wm[e, h*32+v]   (bf16 out)
// ---------------------------------------------------------------------------
__launch_bounds__(64)
__global__ void m_kernel(const float* __restrict__ KV,
                         const float* __restrict__ Wm,
                         short* __restrict__ Mt) {
    const int blk  = blockIdx.x;            // 512 = 8b * 8h * 8 e-tiles
    const int e0   = (blk & 7) * 32;
    const int h    = (blk >> 3) & 7;
    const int b    = blk >> 6;
    const int lane = threadIdx.x;
    const int l31  = lane & 31;
    const int q    = lane >> 5;

    floatx16 acc;
    #pragma unroll
    for (int i = 0; i < 16; i++) acc[i] = 0.f;

    #pragma unroll
    for (int kb = 0; kb < 32; kb += 16) {
        const float* ar = KV + (size_t)(((b * 8 + h) * 32 + l31) * 32) + kb + q * 8;
        const float* br = Wm + (size_t)(e0 + l31) * EMB + h * 32 + kb + q * 8;
        short8 a, w;
        #pragma unroll
        for (int t = 0; t < 8; t++) { a[t] = f2b(ar[t]); w[t] = f2b(br[t]); }
        acc = __builtin_amdgcn_mfma_f32_32x32x16_bf16(a, w, acc, 0, 0, 0);
    }

    short* mrow = Mt + (size_t)b * EMB * EMB + (size_t)(e0 + l31) * EMB + h * 32;
    #pragma unroll
    for (int r4 = 0; r4 < 4; r4++) {
        const int dbase = 8 * r4 + 4 * q;   // row = (reg&3) + 8*(reg>>2) + 4*(lane>>5)
        short4 s4 = make_short4(f2b(acc[r4 * 4 + 0]), f2b(acc[r4 * 4 + 1]),
                                f2b(acc[r4 * 4 + 2]), f2b(acc[r4 * 4 + 3]));
        *(short4*)(mrow + dbase) = s4;
    }
}

// ---------------------------------------------------------------------------
// out[t,e] = sum_hd (Qf[t,hd] * zs[t,h]) * Mt[b][e][hd]
// zs[t,h] = SEQ / (Qf[t,h,:]·Ksum[b,h,:] + 1e-6)
// ---------------------------------------------------------------------------
__launch_bounds__(256)
__global__ void out_kernel(const short* __restrict__ Qf,
                           const float* __restrict__ Ksum,
                           const short* __restrict__ Mt,
                           float* __restrict__ Out) {
    __shared__ __align__(16) short As[128 * 64];
    __shared__ __align__(16) short Bs[128 * 64];
    __shared__ float zs[128][NHD];
    __shared__ float ksl[EMB];

    const int tid  = threadIdx.x;
    const int tm   = blockIdx.x;
    const int tn   = blockIdx.y;
    const int b    = (tm * 128) / SEQ;
    const int lane = tid & 63;
    const int wave = tid >> 6;
    const int wm   = (wave & 1) << 6;
    const int wn   = (wave >> 1) << 6;
    const int fr   = lane & 15;
    const int fq   = lane >> 4;

    ksl[tid] = Ksum[b * EMB + tid];
    __syncthreads();

    {
        const int t  = tid >> 1;
        const int h0 = (tid & 1) * 4;
        const short* qrow = Qf + (size_t)(tm * 128 + t) * EMB;
        #pragma unroll
        for (int hh = 0; hh < 4; hh++) {
            const int h = h0 + hh;
            float d = 0.f;
            #pragma unroll
            for (int u = 0; u < 8; u++) {
                short4 q4 = *(const short4*)(qrow + h * 32 + 4 * u);
                d += b2f(q4.x) * ksl[h * 32 + 4 * u + 0] + b2f(q4.y) * ksl[h * 32 + 4 * u + 1]
                   + b2f(q4.z) * ksl[h * 32 + 4 * u + 2] + b2f(q4.w) * ksl[h * 32 + 4 * u + 3];
            }
            zs[t][h] = (float)SEQ / (d + 1e-6f);
        }
    }
    __syncthreads();

    floatx4 acc[4][4];
    #pragma unroll
    for (int i = 0; i < 4; i++)
        #pragma unroll
        for (int j = 0; j < 4; j++)
            #pragma unroll
            for (int r = 0; r < 4; r++) acc[i][j][r] = 0.f;

    const int r  = tid >> 1;
    const int c0 = (tid & 1) << 5;
    const short* ap = Qf + (size_t)(tm * 128 + r) * EMB + c0;
    const short* bp = Mt + (size_t)b * EMB * EMB + (size_t)(tn * 128 + r) * EMB + c0;

    for (int kc = 0; kc < 4; kc++) {
        const int kb = kc * 64;
        const int h  = (kb + c0) >> 5;
        const float z = zs[r][h];
        #pragma unroll
        for (int u = 0; u < 8; u++) {
            short4 q4 = *(const short4*)(ap + kb + 4 * u);
            short4 oa = make_short4(f2b(b2f(q4.x) * z), f2b(b2f(q4.y) * z),
                                    f2b(b2f(q4.z) * z), f2b(b2f(q4.w) * z));
            *(short4*)&As[r * 64 + c0 + 4 * u] = oa;
            *(short4*)&Bs[r * 64 + c0 + 4 * u] = *(const short4*)(bp + kb + 4 * u);
        }
        __syncthreads();
        #pragma unroll
        for (int kk = 0; kk < 64; kk += 32) {
            short8 a[4], bb[4];
            #pragma unroll
            for (int i = 0; i < 4; i++)
                a[i] = *(const short8*)&As[(wm + i * 16 + fr) * 64 + kk + fq * 8];
            #pragma unroll
            for (int j = 0; j < 4; j++)
                bb[j] = *(const short8*)&Bs[(wn + j * 16 + fr) * 64 + kk + fq * 8];
            #pragma unroll
            for (int i = 0; i < 4; i++)
                #pragma unroll
                for (int j = 0; j < 4; j++)
                    acc[i][j] = __builtin_amdgcn_mfma_f32_16x16x32_bf16(a[i], bb[j], acc[i][j], 0, 0, 0);
        }
        __syncthreads();
    }

    const int row0 = tm * 128;
    #pragma unroll
    for (int i = 0; i < 4; i++) {
        #pragma unroll
        for (int j = 0; j < 4; j++) {
            const int colg = tn * 128 + wn + j * 16 + fr;
            #pragma unroll
            for (int rr = 0; rr < 4; rr++) {
                const int rowg = row0 + wm + i * 16 + fq * 4 + rr;
                Out[(size_t)rowg * EMB + colg] = acc[i][j][rr];
            }
        }
    }
}

extern "C" void kernel_launch(void* const* d_in, const int* in_sizes, int n_in,
                              void* d_out, int out_size, void* d_ws, size_t ws_size,
                              hipStream_t stream) {
    (void)in_sizes; (void)n_in; (void)out_size;
    const float* q  = (const float*)d_in[0];
    const float* k  = (const float*)d_in[1];
    const float* v  = (const float*)d_in[2];
    const float* Wq = (const float*)d_in[3];
    const float* bq = (const float*)d_in[4];
    const float* Wk = (const float*)d_in[5];
    const float* bk = (const float*)d_in[6];
    const float* Wv = (const float*)d_in[7];
    const float* bv = (const float*)d_in[8];
    const float* Wm = (const float*)d_in[9];

    char* ws = (char*)d_ws;
    short* Qf   = (short*)(ws);                                   // 32 MB bf16
    short* Kf   = (short*)(ws + 33554432);                        // 32 MB bf16
    short* Vn   = (short*)(ws + 67108864);                        // 32 MB bf16
    float* Ksum = (float*)(ws + 100663296);                       // 8 KB
    float* KV   = (float*)(ws + 100663296 + 8192);                // 256 KB
    short* Mt   = (short*)(ws + 100663296 + 8192 + 262144);       // 1 MB bf16
    const size_t kvp_off = 100663296ull + 8192 + 262144 + 1048576;
    float* KVp  = (float*)(ws + kvp_off);                         // kvsp*256 KB

    // runtime split-count selection from ws_size (constant per process -> graph-safe)
    int kvsp = 0;
    if      (ws_size >= kvp_off + 64ull * 262144) kvsp = 64;
    else if (ws_size >= kvp_off + 32ull * 262144) kvsp = 32;
    else if (ws_size >= kvp_off + 16ull * 262144) kvsp = 16;

    hipMemsetAsync(ws + 100663296, 0, 8192 + 262144, stream);

    dim3 grid(512, 2), blk(256);
    proj_kernel<0><<<grid, blk, 0, stream>>>(q, Wq, bq, Qf, nullptr);
    proj_kernel<1><<<grid, blk, 0, stream>>>(k, Wk, bk, Kf, Ksum);
    proj_kernel<2><<<grid, blk, 0, stream>>>(v, Wv, bv, Vn, nullptr);

    if (kvsp) {
        kv_kernel<false><<<NB * kvsp, 256, 0, stream>>>(Kf, Vn, KVp, kvsp);
        kvred_kernel<<<64, 256, 0, stream>>>(KVp, KV, kvsp);
    } else {
        kv_kernel<true><<<NB * 16, 256, 0, stream>>>(Kf, Vn, KV, 16);
    }

    m_kernel<<<512, 64, 0, stream>>>(KV, Wm, Mt);
    out_kernel<<<grid, blk, 0, stream>>>(Qf, Ksum, Mt, (float*)d_out);
}

// Round 3
// 373.719 us; speedup vs baseline: 1.2462x; 1.1488x over previous
//
#include <hip/hip_runtime.h>
#include <hip/hip_bf16.h>

#define SEQ   8192
#define NB    8
#define EMB   256
#define NHD   8
#define HDM   32
#define LDP   72   // padded LDS row stride in shorts: 144 B = 9*16 B, bank-rotate by 4

typedef __attribute__((ext_vector_type(8))) short short8;
typedef __attribute__((ext_vector_type(4))) float floatx4;
typedef __attribute__((ext_vector_type(16))) float floatx16;

__device__ __forceinline__ short f2b(float f) {
    __hip_bfloat16 h = __float2bfloat16(f);
    return __builtin_bit_cast(short, h);
}
__device__ __forceinline__ float b2f(short s) {
    unsigned u = (unsigned)(unsigned short)s << 16;
    return __builtin_bit_cast(float, u);
}

// ---------------------------------------------------------------------------
// Fused QKV projection: z=0 -> Qf (elu+1), z=1 -> Kf (elu+1, +Ksum), z=2 -> Vn (/SEQ)
// out[M=65536, N=256] = f( X[M,256] @ W[N,256]^T + bias ), 128x128 tile/block.
// Coalesced fp32 staging (16 B/lane contiguous) + padded LDS (<=2-way banks).
// ---------------------------------------------------------------------------
__launch_bounds__(256)
__global__ void qkv_kernel(const float* __restrict__ qin,
                           const float* __restrict__ kin,
                           const float* __restrict__ vin,
                           const float* __restrict__ Wq, const float* __restrict__ bq,
                           const float* __restrict__ Wk, const float* __restrict__ bk,
                           const float* __restrict__ Wv, const float* __restrict__ bv,
                           short* __restrict__ Qf, short* __restrict__ Kf,
                           short* __restrict__ Vn,
                           float* __restrict__ Ksum) {
    __shared__ __align__(16) short As[128 * LDP];
    __shared__ __align__(16) short Bs[128 * LDP];
    __shared__ float colsum[128];

    const int tid  = threadIdx.x;
    const int tm   = blockIdx.x;
    const int tn   = blockIdx.y;
    const int mode = blockIdx.z;
    const int lane = tid & 63;
    const int wave = tid >> 6;
    const int wm   = (wave & 1) << 6;
    const int wn   = (wave >> 1) << 6;
    const int fr   = lane & 15;
    const int fq   = lane >> 4;

    const float* X    = (mode == 0) ? qin : (mode == 1) ? kin : vin;
    const float* W    = (mode == 0) ? Wq  : (mode == 1) ? Wk  : Wv;
    const float* bias = (mode == 0) ? bq  : (mode == 1) ? bk  : bv;
    short*       out  = (mode == 0) ? Qf  : (mode == 1) ? Kf  : Vn;

    if (mode == 1 && tid < 128) colsum[tid] = 0.f;

    floatx4 acc[4][4];
    #pragma unroll
    for (int i = 0; i < 4; i++)
        #pragma unroll
        for (int j = 0; j < 4; j++)
            #pragma unroll
            for (int r = 0; r < 4; r++) acc[i][j][r] = 0.f;

    const float* Xb = X + (size_t)(tm * 128) * EMB;
    const float* Wb = W + (size_t)(tn * 128) * EMB;

    for (int kc = 0; kc < 4; kc++) {
        const int kb = kc * 64;
        // staging: 2048 float4-chunks per operand, 8 per thread, coalesced
        #pragma unroll
        for (int u = 0; u < 8; u++) {
            const int g   = u * 256 + tid;
            const int row = g >> 4;
            const int c4  = (g & 15) * 4;
            float4 f = *(const float4*)(Xb + (size_t)row * EMB + kb + c4);
            *(short4*)&As[row * LDP + c4] =
                make_short4(f2b(f.x), f2b(f.y), f2b(f.z), f2b(f.w));
            float4 g4 = *(const float4*)(Wb + (size_t)row * EMB + kb + c4);
            *(short4*)&Bs[row * LDP + c4] =
                make_short4(f2b(g4.x), f2b(g4.y), f2b(g4.z), f2b(g4.w));
        }
        __syncthreads();
        #pragma unroll
        for (int kk = 0; kk < 64; kk += 32) {
            short8 a[4], b[4];
            #pragma unroll
            for (int i = 0; i < 4; i++)
                a[i] = *(const short8*)&As[(wm + i * 16 + fr) * LDP + kk + fq * 8];
            #pragma unroll
            for (int j = 0; j < 4; j++)
                b[j] = *(const short8*)&Bs[(wn + j * 16 + fr) * LDP + kk + fq * 8];
            #pragma unroll
            for (int i = 0; i < 4; i++)
                #pragma unroll
                for (int j = 0; j < 4; j++)
                    acc[i][j] = __builtin_amdgcn_mfma_f32_16x16x32_bf16(a[i], b[j], acc[i][j], 0, 0, 0);
        }
        __syncthreads();
    }

    const int row0 = tm * 128;
    float ks[4] = {0.f, 0.f, 0.f, 0.f};
    #pragma unroll
    for (int i = 0; i < 4; i++) {
        #pragma unroll
        for (int j = 0; j < 4; j++) {
            const int colg = tn * 128 + wn + j * 16 + fr;
            const float bia = bias[colg];
            #pragma unroll
            for (int rr = 0; rr < 4; rr++) {
                const int rowg = row0 + wm + i * 16 + fq * 4 + rr;
                float v = acc[i][j][rr] + bia;
                if (mode <= 1) v = (v > 0.f) ? (v + 1.f) : __expf(v);   // elu(x)+1
                else           v *= (1.0f / (float)SEQ);
                out[(size_t)rowg * EMB + colg] = f2b(v);
                ks[j] += v;
            }
        }
    }
    if (mode == 1) {
        #pragma unroll
        for (int j = 0; j < 4; j++)
            atomicAdd(&colsum[wn + j * 16 + fr], ks[j]);
        __syncthreads();
        if (tid < 128) {
            const int b = (tm * 128) / SEQ;
            atomicAdd(&Ksum[b * EMB + tn * 128 + tid], colsum[tid]);
        }
    }
}

// ---------------------------------------------------------------------------
// KV partials: block (b,sp) stages 32-row tiles of Kf,Vn, 4 waves x 2 heads,
// per-lane 4x8 register outer product.
// ---------------------------------------------------------------------------
template <bool ATOMIC>
__launch_bounds__(256)
__global__ void kv_kernel(const short* __restrict__ Kf,
                          const short* __restrict__ Vn,
                          float* __restrict__ dst_base,
                          int kvsp) {
    __shared__ __align__(16) short Kt[32 * 256];
    __shared__ __align__(16) short Vt[32 * 256];

    const int tid  = threadIdx.x;
    const int sp   = blockIdx.x % kvsp;
    const int b    = blockIdx.x / kvsp;
    const int wave = tid >> 6;
    const int lane = tid & 63;
    const int h    = wave * 2 + (lane >> 5);
    const int l5   = lane & 31;
    const int d0   = (l5 >> 2) * 4;
    const int v0   = (l5 & 3) * 8;
    const int chunk = SEQ / kvsp;
    const size_t rowbase = (size_t)(b * SEQ + sp * chunk) * EMB;

    float acc[4][8];
    #pragma unroll
    for (int i = 0; i < 4; i++)
        #pragma unroll
        for (int j = 0; j < 8; j++) acc[i][j] = 0.f;

    for (int t0 = 0; t0 < chunk; t0 += 32) {
        __syncthreads();
        const short* ksrc = Kf + rowbase + (size_t)t0 * EMB;
        const short* vsrc = Vn + rowbase + (size_t)t0 * EMB;
        #pragma unroll
        for (int u = 0; u < 4; u++) {
            const int c   = tid + u * 256;
            const int row = c >> 5;
            const int col = (c & 31) * 8;
            *(short8*)&Kt[row * 256 + col] = *(const short8*)(ksrc + (size_t)row * EMB + col);
            *(short8*)&Vt[row * 256 + col] = *(const short8*)(vsrc + (size_t)row * EMB + col);
        }
        __syncthreads();
        #pragma unroll 4
        for (int s = 0; s < 32; s++) {
            short4 k4 = *(const short4*)&Kt[s * 256 + h * 32 + d0];
            short8 v8 = *(const short8*)&Vt[s * 256 + h * 32 + v0];
            float kf[4] = {b2f(k4.x), b2f(k4.y), b2f(k4.z), b2f(k4.w)};
            float vf[8];
            #pragma unroll
            for (int j = 0; j < 8; j++) vf[j] = b2f(v8[j]);
            #pragma unroll
            for (int i = 0; i < 4; i++)
                #pragma unroll
                for (int j = 0; j < 8; j++) acc[i][j] += kf[i] * vf[j];
        }
    }

    if (ATOMIC) {
        float* dst = dst_base + (size_t)((b * 8 + h) * 1024);
        #pragma unroll
        for (int i = 0; i < 4; i++)
            #pragma unroll
            for (int j = 0; j < 8; j++)
                atomicAdd(&dst[(d0 + i) * 32 + v0 + j], acc[i][j]);
    } else {
        float* dst = dst_base + (size_t)(((size_t)sp * NB + b) * 8 + h) * 1024;
        #pragma unroll
        for (int i = 0; i < 4; i++) {
            float4 lo = make_float4(acc[i][0], acc[i][1], acc[i][2], acc[i][3]);
            float4 hi = make_float4(acc[i][4], acc[i][5], acc[i][6], acc[i][7]);
            *(float4*)&dst[(d0 + i) * 32 + v0]     = lo;
            *(float4*)&dst[(d0 + i) * 32 + v0 + 4] = hi;
        }
    }
}

// KV[i] = sum_sp KVp[sp][i],  i < 65536
__launch_bounds__(256)
__global__ void kvred_kernel(const float* __restrict__ KVp,
                             float* __restrict__ KV, int kvsp) {
    const int i = blockIdx.x * 1024 + threadIdx.x * 4;
    float4 s = make_float4(0.f, 0.f, 0.f, 0.f);
    for (int p = 0; p < kvsp; p++) {
        float4 t = *(const float4*)&KVp[(size_t)p * 65536 + i];
        s.x += t.x; s.y += t.y; s.z += t.z; s.w += t.w;
    }
    *(float4*)&KV[i] = s;
}

// ---------------------------------------------------------------------------
// Mt[b][e][h*32+d] = sum_v KV[b,h,d,v] * Wm[e, h*32+v]   (bf16 out)
// ---------------------------------------------------------------------------
__launch_bounds__(64)
__global__ void m_kernel(const float* __restrict__ KV,
                         const float* __restrict__ Wm,
                         short* __restrict__ Mt) {
    const int blk  = blockIdx.x;            // 512 = 8b * 8h * 8 e-tiles
    const int e0   = (blk & 7) * 32;
    const int h    = (blk >> 3) & 7;
    const int b    = blk >> 6;
    const int lane = threadIdx.x;
    const int l31  = lane & 31;
    const int q    = lane >> 5;

    floatx16 acc;
    #pragma unroll
    for (int i = 0; i < 16; i++) acc[i] = 0.f;

    #pragma unroll
    for (int kb = 0; kb < 32; kb += 16) {
        const float* ar = KV + (size_t)(((b * 8 + h) * 32 + l31) * 32) + kb + q * 8;
        const float* br = Wm + (size_t)(e0 + l31) * EMB + h * 32 + kb + q * 8;
        short8 a, w;
        #pragma unroll
        for (int t = 0; t < 8; t++) { a[t] = f2b(ar[t]); w[t] = f2b(br[t]); }
        acc = __builtin_amdgcn_mfma_f32_32x32x16_bf16(a, w, acc, 0, 0, 0);
    }

    short* mrow = Mt + (size_t)b * EMB * EMB + (size_t)(e0 + l31) * EMB + h * 32;
    #pragma unroll
    for (int r4 = 0; r4 < 4; r4++) {
        const int dbase = 8 * r4 + 4 * q;   // row = (reg&3) + 8*(reg>>2) + 4*(lane>>5)
        short4 s4 = make_short4(f2b(acc[r4 * 4 + 0]), f2b(acc[r4 * 4 + 1]),
                                f2b(acc[r4 * 4 + 2]), f2b(acc[r4 * 4 + 3]));
        *(short4*)(mrow + dbase) = s4;
    }
}

// ---------------------------------------------------------------------------
// out[t,e] = sum_hd (Qf[t,hd] * zs[t,h]) * Mt[b][e][hd]
// zs[t,h] = SEQ / (Qf[t,h,:]·Ksum[b,h,:] + 1e-6)
// ---------------------------------------------------------------------------
__launch_bounds__(256)
__global__ void out_kernel(const short* __restrict__ Qf,
                           const float* __restrict__ Ksum,
                           const short* __restrict__ Mt,
                           float* __restrict__ Out) {
    __shared__ __align__(16) short As[128 * LDP];
    __shared__ __align__(16) short Bs[128 * LDP];
    __shared__ float zs[128][NHD];
    __shared__ float ksl[EMB];

    const int tid  = threadIdx.x;
    const int tm   = blockIdx.x;
    const int tn   = blockIdx.y;
    const int b    = (tm * 128) / SEQ;
    const int lane = tid & 63;
    const int wave = tid >> 6;
    const int wm   = (wave & 1) << 6;
    const int wn   = (wave >> 1) << 6;
    const int fr   = lane & 15;
    const int fq   = lane >> 4;

    ksl[tid] = Ksum[b * EMB + tid];
    __syncthreads();

    {
        const int t  = tid >> 1;
        const int h0 = (tid & 1) * 4;
        const short* qrow = Qf + (size_t)(tm * 128 + t) * EMB;
        #pragma unroll
        for (int hh = 0; hh < 4; hh++) {
            const int h = h0 + hh;
            float d = 0.f;
            #pragma unroll
            for (int u = 0; u < 8; u++) {
                short4 q4 = *(const short4*)(qrow + h * 32 + 4 * u);
                d += b2f(q4.x) * ksl[h * 32 + 4 * u + 0] + b2f(q4.y) * ksl[h * 32 + 4 * u + 1]
                   + b2f(q4.z) * ksl[h * 32 + 4 * u + 2] + b2f(q4.w) * ksl[h * 32 + 4 * u + 3];
            }
            zs[t][h] = (float)SEQ / (d + 1e-6f);
        }
    }
    __syncthreads();

    floatx4 acc[4][4];
    #pragma unroll
    for (int i = 0; i < 4; i++)
        #pragma unroll
        for (int j = 0; j < 4; j++)
            #pragma unroll
            for (int r = 0; r < 4; r++) acc[i][j][r] = 0.f;

    const short* Ab = Qf + (size_t)(tm * 128) * EMB;
    const short* Bb = Mt + (size_t)b * EMB * EMB + (size_t)(tn * 128) * EMB;

    for (int kc = 0; kc < 4; kc++) {
        const int kb = kc * 64;
        // staging: 1024 short8-chunks per operand, 4 per thread, coalesced
        #pragma unroll
        for (int u = 0; u < 4; u++) {
            const int g   = u * 256 + tid;
            const int row = g >> 3;
            const int c8  = (g & 7) * 8;
            const float z = zs[row][(kb + c8) >> 5];
            short8 qv = *(const short8*)(Ab + (size_t)row * EMB + kb + c8);
            short8 oa;
            #pragma unroll
            for (int t = 0; t < 8; t++) oa[t] = f2b(b2f(qv[t]) * z);
            *(short8*)&As[row * LDP + c8] = oa;
            *(short8*)&Bs[row * LDP + c8] = *(const short8*)(Bb + (size_t)row * EMB + kb + c8);
        }
        __syncthreads();
        #pragma unroll
        for (int kk = 0; kk < 64; kk += 32) {
            short8 a[4], bb[4];
            #pragma unroll
            for (int i = 0; i < 4; i++)
                a[i] = *(const short8*)&As[(wm + i * 16 + fr) * LDP + kk + fq * 8];
            #pragma unroll
            for (int j = 0; j < 4; j++)
                bb[j] = *(const short8*)&Bs[(wn + j * 16 + fr) * LDP + kk + fq * 8];
            #pragma unroll
            for (int i = 0; i < 4; i++)
                #pragma unroll
                for (int j = 0; j < 4; j++)
                    acc[i][j] = __builtin_amdgcn_mfma_f32_16x16x32_bf16(a[i], bb[j], acc[i][j], 0, 0, 0);
        }
        __syncthreads();
    }

    const int row0 = tm * 128;
    #pragma unroll
    for (int i = 0; i < 4; i++) {
        #pragma unroll
        for (int j = 0; j < 4; j++) {
            const int colg = tn * 128 + wn + j * 16 + fr;
            #pragma unroll
            for (int rr = 0; rr < 4; rr++) {
                const int rowg = row0 + wm + i * 16 + fq * 4 + rr;
                Out[(size_t)rowg * EMB + colg] = acc[i][j][rr];
            }
        }
    }
}

extern "C" void kernel_launch(void* const* d_in, const int* in_sizes, int n_in,
                              void* d_out, int out_size, void* d_ws, size_t ws_size,
                              hipStream_t stream) {
    (void)in_sizes; (void)n_in; (void)out_size;
    const float* q  = (const float*)d_in[0];
    const float* k  = (const float*)d_in[1];
    const float* v  = (const float*)d_in[2];
    const float* Wq = (const float*)d_in[3];
    const float* bq = (const float*)d_in[4];
    const float* Wk = (const float*)d_in[5];
    const float* bk = (const float*)d_in[6];
    const float* Wv = (const float*)d_in[7];
    const float* bv = (const float*)d_in[8];
    const float* Wm = (const float*)d_in[9];

    char* ws = (char*)d_ws;
    short* Qf   = (short*)(ws);                                   // 32 MB bf16
    short* Kf   = (short*)(ws + 33554432);                        // 32 MB bf16
    short* Vn   = (short*)(ws + 67108864);                        // 32 MB bf16
    float* Ksum = (float*)(ws + 100663296);                       // 8 KB
    float* KV   = (float*)(ws + 100663296 + 8192);                // 256 KB
    short* Mt   = (short*)(ws + 100663296 + 8192 + 262144);       // 1 MB bf16
    const size_t kvp_off = 100663296ull + 8192 + 262144 + 1048576;
    float* KVp  = (float*)(ws + kvp_off);                         // kvsp*256 KB

    int kvsp = 0;
    if      (ws_size >= kvp_off + 64ull * 262144) kvsp = 64;
    else if (ws_size >= kvp_off + 32ull * 262144) kvsp = 32;
    else if (ws_size >= kvp_off + 16ull * 262144) kvsp = 16;

    hipMemsetAsync(ws + 100663296, 0, 8192 + 262144, stream);

    dim3 blk(256);
    qkv_kernel<<<dim3(512, 2, 3), blk, 0, stream>>>(q, k, v, Wq, bq, Wk, bk, Wv, bv,
                                                    Qf, Kf, Vn, Ksum);

    if (kvsp) {
        kv_kernel<false><<<NB * kvsp, 256, 0, stream>>>(Kf, Vn, KVp, kvsp);
        kvred_kernel<<<64, 256, 0, stream>>>(KVp, KV, kvsp);
    } else {
        kv_kernel<true><<<NB * 16, 256, 0, stream>>>(Kf, Vn, KV, 16);
    }

    m_kernel<<<512, 64, 0, stream>>>(KV, Wm, Mt);
    out_kernel<<<dim3(512, 2), blk, 0, stream>>>(Qf, Ksum, Mt, (float*)d_out);
}